// Round 2
// baseline (513.395 us; speedup 1.0000x reference)
//
#include <hip/hip_runtime.h>
#include <hip/hip_bf16.h>
#include <stdint.h>

// LayerNormLSTM: T=512, B=64, I=1024, H=1024
// M = T*B = 32768 rows, N = 4*H = 4096, K = 1024.
// Reference degenerates (h0=c0=0, no scan):
//   h2h_vec = LN(bh; g_h2h, b_h2h)            (constant 4096-vec; Wh unused)
//   y       = x @ Wi^T                         (big GEMM -> 256^2 8-phase template)
//   p       = g_i2h * LNrow(y + bi) + (b_i2h + h2h_vec)
//   f,o     = sigmoid(p[H:2H]), sigmoid(p[2H:3H]); g = tanh(p[3H:])
//   c       = (1-f)*g ;  cn = LN_H(c) ;  h = o * tanh(cn)
// out = [h (T,B,H) ; h[-1] (B,H)]

#define MROWS 32768L
#define NCOLS 4096
#define KDIM  1024

typedef __bf16 bf16x8 __attribute__((ext_vector_type(8)));
typedef __bf16 bf16x4 __attribute__((ext_vector_type(4)));
typedef float  f32x4  __attribute__((ext_vector_type(4)));

__device__ float g_Cvec[4096];   // b_i2h + h2h_vec (recomputed every launch)

__device__ __forceinline__ void gload16(char* lds, const char* g) {
  __builtin_amdgcn_global_load_lds(
      (const __attribute__((address_space(1))) char*)g,
      (__attribute__((address_space(3))) char*)lds, 16, 0, 0);
}

__device__ __forceinline__ void block_reduce2(float& a, float& b, float* red, int tid) {
#pragma unroll
  for (int m = 32; m > 0; m >>= 1) {
    a += __shfl_xor(a, m, 64);
    b += __shfl_xor(b, m, 64);
  }
  const int lane = tid & 63, wid = tid >> 6;
  if (lane == 0) { red[wid] = a; red[4 + wid] = b; }
  __syncthreads();
  a = red[0] + red[1] + red[2] + red[3];
  b = red[4] + red[5] + red[6] + red[7];
  __syncthreads();  // safe reuse of red[]
}

// ---------------- cast f32 -> bf16 (vectorized) ----------------
__global__ __launch_bounds__(256) void cast_kernel(const float4* __restrict__ in,
                                                   bf16x4* __restrict__ out, int n4) {
  int i = blockIdx.x * 256 + threadIdx.x;
  const int stride = gridDim.x * 256;
  for (; i < n4; i += stride) {
    const float4 v = in[i];
    bf16x4 o = { (__bf16)v.x, (__bf16)v.y, (__bf16)v.z, (__bf16)v.w };
    out[i] = o;
  }
}

// ---------------- prep: Cvec = b_i2h + LN(bh)*g_h2h + b_h2h ----------------
__global__ __launch_bounds__(256) void prep_kernel(const float* __restrict__ bh,
                                                   const float* __restrict__ b_i2h,
                                                   const float* __restrict__ g_h2h,
                                                   const float* __restrict__ b_h2h) {
  __shared__ float red[8];
  const int tid = threadIdx.x;
  float v[16];
  float s = 0.f, ss = 0.f;
#pragma unroll
  for (int u = 0; u < 16; ++u) {
    v[u] = bh[tid + u * 256];
    s += v[u]; ss += v[u] * v[u];
  }
  block_reduce2(s, ss, red, tid);
  const float mu  = s * (1.f / 4096.f);
  const float var = (ss - 4096.f * mu * mu) * (1.f / 4095.f);   // ddof=1
  const float rs  = rsqrtf(var + 1e-6f);
#pragma unroll
  for (int u = 0; u < 16; ++u) {
    const int g = tid + u * 256;
    g_Cvec[g] = b_i2h[g] + g_h2h[g] * ((v[u] - mu) * rs) + b_h2h[g];
  }
}

// ---------------- GEMM: Y[m][n] = sum_k A[m][k]*B[n][k]  (bf16 in, bf16 out) ----
// 256^2 8-phase template (m201): BM=BN=256, BK=64, 8 waves (2Mx4N), 128KiB LDS
// [2 dbuf][2 half][128][64], st_16x32 swizzle (byte ^= ((byte>>9)&1)<<5),
// counted vmcnt(4) at K-tile boundaries, setprio(1) around MFMA clusters.
//
// Per K-tile t (4 phases, ds_reads {12,8,4,0}):
//  q0: RD Aa(8)+B01(4); STAGE B(t+1,h0); bar; lgkm0; MFMA acc[0-3][0-1]; bar
//  q1: RD Ab(8);        STAGE B(t+1,h1); bar; lgkm0; MFMA acc[4-7][0-1]; bar
//  q2: RD B23(4);       STAGE A(t+2,h0); bar; lgkm0; MFMA acc[4-7][2-3]; bar
//  q3: (reuse Aa,B23);  STAGE A(t+2,h1); bar; lgkm0; MFMA acc[0-3][2-3]; vmcnt(4); bar
// Race-safety: A halves of buf[t&1] last ds_read at q1 -> A staging at q2/q3 OK.
// B staging targets buf[(t+1)&1], last read at (t-1).q2 -> q0/q1 OK.
// vmcnt(4): newest 4 in-flight loads are t+2's A -> everything <= B(t+1,h1) landed.

#define PH_MID() do { asm volatile("" ::: "memory"); __builtin_amdgcn_s_barrier(); \
    asm volatile("s_waitcnt lgkmcnt(0)" ::: "memory"); \
    __builtin_amdgcn_sched_barrier(0); __builtin_amdgcn_s_setprio(1); } while (0)

#define PH_END() do { __builtin_amdgcn_s_setprio(0); \
    asm volatile("" ::: "memory"); __builtin_amdgcn_s_barrier(); } while (0)

#define STG_A(s, h) { char* d_ = Al + (((s) & 1) << 15) + ((h) << 14); \
    const char* g_ = Ag + (long)(h) * 262144 + (s) * 128; \
    gload16(d_, g_); gload16(d_ + 8192, g_ + 131072); }

#define STG_B(s, h) { char* d_ = Bl + (((s) & 1) << 15) + ((h) << 14); \
    const char* g_ = Bg + (long)(h) * 262144 + (s) * 128; \
    gload16(d_, g_); gload16(d_ + 8192, g_ + 131072); }

#define RD_A(arr, c) { _Pragma("unroll") for (int mi_ = 0; mi_ < 4; ++mi_) { \
    const char* p_ = Ahalf + (((c) * 64 + mi_ * 16 + fr) << 7); \
    arr[mi_][0] = *(const bf16x8*)(p_ + cb0); \
    arr[mi_][1] = *(const bf16x8*)(p_ + cb1); } }

#define RD_B(g) { _Pragma("unroll") for (int nj_ = 0; nj_ < 2; ++nj_) { \
    const char* p_ = Bhalf + ((brow0 + (g) * 32 + nj_ * 16 + fr) << 7); \
    b[nj_][0] = *(const bf16x8*)(p_ + cb0); \
    b[nj_][1] = *(const bf16x8*)(p_ + cb1); } }

#define MM_Q(arr, c, g) { _Pragma("unroll") for (int mi_ = 0; mi_ < 4; ++mi_) { \
    _Pragma("unroll") for (int nj_ = 0; nj_ < 2; ++nj_) { \
      acc[(c)*4+mi_][(g)*2+nj_] = __builtin_amdgcn_mfma_f32_16x16x32_bf16( \
          arr[mi_][0], b[nj_][0], acc[(c)*4+mi_][(g)*2+nj_], 0, 0, 0); \
      acc[(c)*4+mi_][(g)*2+nj_] = __builtin_amdgcn_mfma_f32_16x16x32_bf16( \
          arr[mi_][1], b[nj_][1], acc[(c)*4+mi_][(g)*2+nj_], 0, 0, 0); } } }

__global__ __launch_bounds__(512, 2) void gemm_kernel(const __bf16* __restrict__ A,
                                                      const __bf16* __restrict__ B,
                                                      __bf16* __restrict__ Y, long r0) {
  __shared__ __align__(16) __bf16 As[2 * 2 * 8192];   // [buf][half][128][64] swizzled
  __shared__ __align__(16) __bf16 Bs[2 * 2 * 8192];

  const int tid  = threadIdx.x;
  const int lane = tid & 63;
  const int wid  = tid >> 6;        // 0..7
  const int wr   = wid >> 2;        // 0..1  (M half)
  const int wc   = wid & 3;         // 0..3  (N quarter)

  // bijective XCD-aware swizzle (m204)
  const int nwg = gridDim.x;
  const int q8 = nwg >> 3, r8 = nwg & 7;
  const int xcd = blockIdx.x & 7, rest = blockIdx.x >> 3;
  const int wgid = (xcd < r8 ? xcd * (q8 + 1) : r8 * (q8 + 1) + (xcd - r8) * q8) + rest;
  const long m0 = (long)(wgid >> 4) * 256;   // chunk-local row tile
  const long n0 = (long)(wgid & 15) * 256;

  // staging: dest byte (linear, per half) = j*8192 + tid*16; inverse-swizzled source:
  // row = j*64 + tid/8 (bit9 doesn't touch row), colbyte = (tid&7)*16 ^ ((tid>>5)&1)<<5
  const int scol = ((tid & 7) << 4) ^ (((tid >> 5) & 1) << 5);
  const char* Ag = (const char*)(A + (r0 + m0) * KDIM) + (long)(tid >> 3) * 2048 + scol;
  const char* Bg = (const char*)(B + n0 * KDIM) + (long)(tid >> 3) * 2048 + scol;
  char* Al = (char*)As + tid * 16;
  char* Bl = (char*)Bs + tid * 16;

  // fragment read addressing: logical off = lr*128 + ks*64 + kg*16;
  // bit9 of off = (lr>>2)&1 = (fr>>2)&1  ->  constant per-lane XOR (fr&4)<<3
  const int fr  = lane & 15;
  const int cb0 = (((lane >> 4) << 4)) ^ ((fr & 4) << 3);
  const int cb1 = (64 + ((lane >> 4) << 4)) ^ ((fr & 4) << 3);
  const int brow0 = (wc & 1) << 6;

  f32x4 acc[8][4];
  const f32x4 z = {0.f, 0.f, 0.f, 0.f};
#pragma unroll
  for (int i = 0; i < 8; ++i)
#pragma unroll
    for (int j = 0; j < 4; ++j) acc[i][j] = z;

  // ---- prologue: 6 half-tiles (tile0 complete + tile1 A halves), per-wave 12 loads
  STG_A(0, 0); STG_A(0, 1); STG_B(0, 0); STG_B(0, 1); STG_A(1, 0); STG_A(1, 1);
  asm volatile("s_waitcnt vmcnt(4)" ::: "memory");   // tile0 fully landed
  __builtin_amdgcn_s_barrier();

  bf16x8 aa[4][2], ab[4][2], b[2][2];

#pragma unroll 2
  for (int t = 0; t < 16; ++t) {
    const char* Ahalf = (const char*)As + ((t & 1) << 15) + (wr << 14);
    const char* Bhalf = (const char*)Bs + ((t & 1) << 15) + ((wc >> 1) << 14);

    // q0
    RD_A(aa, 0); RD_B(0);
    if (t + 1 < 16) STG_B(t + 1, 0);
    PH_MID(); MM_Q(aa, 0, 0); PH_END();
    // q1
    RD_A(ab, 1);
    if (t + 1 < 16) STG_B(t + 1, 1);
    PH_MID(); MM_Q(ab, 1, 0); PH_END();
    // q2
    RD_B(1);
    if (t + 2 < 16) STG_A(t + 2, 0);
    PH_MID(); MM_Q(ab, 1, 1); PH_END();
    // q3 (reuse aa + b23)
    if (t + 2 < 16) STG_A(t + 2, 1);
    PH_MID(); MM_Q(aa, 0, 1);
    __builtin_amdgcn_s_setprio(0);
    if (t == 14)      { asm volatile("s_waitcnt vmcnt(0)" ::: "memory"); }
    else if (t < 14)  { asm volatile("s_waitcnt vmcnt(4)" ::: "memory"); }
    asm volatile("" ::: "memory");
    __builtin_amdgcn_s_barrier();
  }

  // ---- epilogue: C/D layout col=lane&15, row=(lane>>4)*4+reg
  const long mrow = m0 + wr * 128 + ((lane >> 4) << 2);
  const long ncol = n0 + wc * 64 + fr;
  __bf16* Yp = Y + mrow * NCOLS + ncol;
#pragma unroll
  for (int c = 0; c < 2; ++c)
#pragma unroll
    for (int mi = 0; mi < 4; ++mi)
#pragma unroll
      for (int nj = 0; nj < 4; ++nj)
#pragma unroll
        for (int r = 0; r < 4; ++r)
          Yp[(long)(c * 64 + mi * 16 + r) * NCOLS + nj * 16] = (__bf16)acc[c * 4 + mi][nj][r];
}

// ---------------- pass 2: row LN + gates + cell LN + output ----------------
__global__ __launch_bounds__(256) void pass2_kernel(const __bf16* __restrict__ Yw,
                                                    const float* __restrict__ bi,
                                                    const float* __restrict__ g_i2h,
                                                    const float* __restrict__ g_cell,
                                                    const float* __restrict__ b_cell,
                                                    float* __restrict__ out, long r0) {
  __shared__ float p0[4096];
  __shared__ float red[8];
  const int tid  = threadIdx.x;
  const long row = r0 + blockIdx.x;           // global row (t*64 + b)
  const bf16x8* yv = (const bf16x8*)(Yw + (long)blockIdx.x * NCOLS);

  // phase 1: p = y + bi (fp32), stash in LDS, accumulate stats over 4096
  float s = 0.f, ss = 0.f;
#pragma unroll
  for (int it = 0; it < 2; ++it) {
    const int ch = tid + it * 256;            // 8-elem chunk id, 0..511
    const bf16x8 v = yv[ch];
    const float4 b0 = ((const float4*)bi)[ch * 2];
    const float4 b1 = ((const float4*)bi)[ch * 2 + 1];
    float p[8];
    p[0] = (float)v[0] + b0.x;  p[1] = (float)v[1] + b0.y;
    p[2] = (float)v[2] + b0.z;  p[3] = (float)v[3] + b0.w;
    p[4] = (float)v[4] + b1.x;  p[5] = (float)v[5] + b1.y;
    p[6] = (float)v[6] + b1.z;  p[7] = (float)v[7] + b1.w;
#pragma unroll
    for (int u = 0; u < 8; ++u) {
      p0[ch * 8 + u] = p[u];
      s += p[u];
      ss += p[u] * p[u];
    }
  }
  block_reduce2(s, ss, red, tid);             // also fences p0 writes
  const float mu  = s * (1.f / 4096.f);
  const float var = (ss - 4096.f * mu * mu) * (1.f / 4095.f);   // ddof=1
  const float rs  = rsqrtf(var + 1e-6f);

  // phase 2: gates + cell accumulation (j = tid + u*256)
  float cc[4], oo[4];
  float s2 = 0.f, ss2 = 0.f;
#pragma unroll
  for (int u = 0; u < 4; ++u) {
    const int j = tid + u * 256;
    const float pf = g_i2h[1024 + j] * ((p0[1024 + j] - mu) * rs) + g_Cvec[1024 + j];
    const float po = g_i2h[2048 + j] * ((p0[2048 + j] - mu) * rs) + g_Cvec[2048 + j];
    const float pg = g_i2h[3072 + j] * ((p0[3072 + j] - mu) * rs) + g_Cvec[3072 + j];
    const float f  = 1.f / (1.f + __expf(-pf));
    oo[u] = 1.f / (1.f + __expf(-po));
    const float e2 = __expf(2.f * pg);
    const float gt = (e2 - 1.f) / (e2 + 1.f);   // tanh
    cc[u] = (1.f - f) * gt;                     // c0 = 0
    s2 += cc[u]; ss2 += cc[u] * cc[u];
  }
  block_reduce2(s2, ss2, red, tid);
  const float mu2  = s2 * (1.f / 1024.f);
  const float var2 = (ss2 - 1024.f * mu2 * mu2) * (1.f / 1023.f);  // ddof=1
  const float rs2  = rsqrtf(var2 + 1e-6f);

  const long obase = row * 1024;
#pragma unroll
  for (int u = 0; u < 4; ++u) {
    const int j = tid + u * 256;
    const float cn = g_cell[j] * ((cc[u] - mu2) * rs2) + b_cell[j];
    const float e2 = __expf(2.f * cn);
    const float th = (e2 - 1.f) / (e2 + 1.f);
    const float h  = oo[u] * th;
    out[obase + j] = h;
    if (row >= MROWS - 64)                       // t == T-1
      out[MROWS * 1024 + ((row - (MROWS - 64)) << 10) + j] = h;
  }
}

extern "C" void kernel_launch(void* const* d_in, const int* in_sizes, int n_in,
                              void* d_out, int out_size, void* d_ws, size_t ws_size,
                              hipStream_t stream) {
  (void)in_sizes; (void)n_in; (void)out_size;
  const float* x      = (const float*)d_in[0];
  const float* Wi     = (const float*)d_in[1];
  const float* bi     = (const float*)d_in[2];
  // d_in[3] = Wh : unused (h0 == 0)
  const float* bh     = (const float*)d_in[4];
  const float* g_i2h  = (const float*)d_in[5];
  const float* b_i2h  = (const float*)d_in[6];
  const float* g_h2h  = (const float*)d_in[7];
  const float* b_h2h  = (const float*)d_in[8];
  const float* g_cell = (const float*)d_in[9];
  const float* b_cell = (const float*)d_in[10];
  float* out = (float*)d_out;

  // Scratch carved from d_out (fully overwritten by pass2 afterwards):
  //   [0, 64MB)    x as bf16
  //   [64MB, 72MB) Wi as bf16
  __bf16* xb = (__bf16*)d_out;
  __bf16* wb = (__bf16*)((char*)d_out + 67108864);
  __bf16* y  = (__bf16*)d_ws;   // Y intermediate, up to 256 MB (chunked if ws smaller)

  cast_kernel<<<2048, 256, 0, stream>>>((const float4*)x, (bf16x4*)xb, 33554432 / 4);
  cast_kernel<<<1024, 256, 0, stream>>>((const float4*)Wi, (bf16x4*)wb, 4194304 / 4);
  prep_kernel<<<1, 256, 0, stream>>>(bh, b_i2h, g_h2h, b_h2h);

  // chunk over M if the workspace can't hold the full 32768x4096 bf16 Y
  long max_rows = (long)(ws_size / (NCOLS * 2)) & ~255L;
  if (max_rows > MROWS) max_rows = MROWS;
  if (max_rows < 256)   max_rows = 256;   // assume ws >= 2 MB
  for (long rbase = 0; rbase < MROWS; rbase += max_rows) {
    const long rows = (MROWS - rbase < max_rows) ? (MROWS - rbase) : max_rows;
    gemm_kernel<<<dim3((rows / 256) * 16), 512, 0, stream>>>(xb, wb, y, rbase);
    pass2_kernel<<<dim3(rows), 256, 0, stream>>>(y, bi, g_i2h, g_cell, b_cell, out, rbase);
  }
}

// Round 3
// 486.759 us; speedup vs baseline: 1.0547x; 1.0547x over previous
//
#include <hip/hip_runtime.h>
#include <hip/hip_bf16.h>
#include <stdint.h>

// LayerNormLSTM: T=512, B=64, I=1024, H=1024
// M = T*B = 32768 rows, N = 4*H = 4096, K = 1024.
// Reference degenerates (h0=c0=0, no scan):
//   h2h_vec = LN(bh; g_h2h, b_h2h)            (constant 4096-vec; Wh unused)
//   y       = x @ Wi^T                         (big GEMM -> 256^2 8-phase template)
//   p       = g_i2h * LNrow(y + bi) + (b_i2h + h2h_vec)
//   f,o     = sigmoid(p[H:2H]), sigmoid(p[2H:3H]); g = tanh(p[3H:])
//   c       = (1-f)*g ;  cn = LN_H(c) ;  h = o * tanh(cn)
// out = [h (T,B,H) ; h[-1] (B,H)]

#define MROWS 32768L
#define NCOLS 4096
#define KDIM  1024

typedef __bf16 bf16x8 __attribute__((ext_vector_type(8)));
typedef __bf16 bf16x4 __attribute__((ext_vector_type(4)));
typedef float  f32x4  __attribute__((ext_vector_type(4)));

__device__ float g_Cvec[4096];   // b_i2h + h2h_vec (recomputed every launch)

__device__ __forceinline__ void gload16(char* lds, const char* g) {
  __builtin_amdgcn_global_load_lds(
      (const __attribute__((address_space(1))) char*)g,
      (__attribute__((address_space(3))) char*)lds, 16, 0, 0);
}

__device__ __forceinline__ void block_reduce2(float& a, float& b, float* red, int tid) {
#pragma unroll
  for (int m = 32; m > 0; m >>= 1) {
    a += __shfl_xor(a, m, 64);
    b += __shfl_xor(b, m, 64);
  }
  const int lane = tid & 63, wid = tid >> 6;
  if (lane == 0) { red[wid] = a; red[4 + wid] = b; }
  __syncthreads();
  a = red[0] + red[1] + red[2] + red[3];
  b = red[4] + red[5] + red[6] + red[7];
  __syncthreads();  // safe reuse of red[]
}

// ---------------- cast f32 -> bf16 (vectorized) ----------------
__global__ __launch_bounds__(256) void cast_kernel(const float4* __restrict__ in,
                                                   bf16x4* __restrict__ out, int n4) {
  int i = blockIdx.x * 256 + threadIdx.x;
  const int stride = gridDim.x * 256;
  for (; i < n4; i += stride) {
    const float4 v = in[i];
    bf16x4 o = { (__bf16)v.x, (__bf16)v.y, (__bf16)v.z, (__bf16)v.w };
    out[i] = o;
  }
}

// ---------------- prep: Cvec = b_i2h + LN(bh)*g_h2h + b_h2h ----------------
__global__ __launch_bounds__(256) void prep_kernel(const float* __restrict__ bh,
                                                   const float* __restrict__ b_i2h,
                                                   const float* __restrict__ g_h2h,
                                                   const float* __restrict__ b_h2h) {
  __shared__ float red[8];
  const int tid = threadIdx.x;
  float v[16];
  float s = 0.f, ss = 0.f;
#pragma unroll
  for (int u = 0; u < 16; ++u) {
    v[u] = bh[tid + u * 256];
    s += v[u]; ss += v[u] * v[u];
  }
  block_reduce2(s, ss, red, tid);
  const float mu  = s * (1.f / 4096.f);
  const float var = (ss - 4096.f * mu * mu) * (1.f / 4095.f);   // ddof=1
  const float rs  = rsqrtf(var + 1e-6f);
#pragma unroll
  for (int u = 0; u < 16; ++u) {
    const int g = tid + u * 256;
    g_Cvec[g] = b_i2h[g] + g_h2h[g] * ((v[u] - mu) * rs) + b_h2h[g];
  }
}

// ---------------- GEMM: Y[m][n] = sum_k A[m][k]*B[n][k]  (bf16 in, bf16 out) ----
// 256^2 8-phase template: BM=BN=256, BK=64, 8 waves (2Mx4N), 128KiB LDS
// [2 dbuf][2 half][128][64], counted vmcnt(4), setprio(1) around MFMA.
//
// LDS swizzle (derived for this layout, R2 post-mortem):
//   row-major [128][64] bf16, ds_read_b128 frags at byte = lr*128 + kg*16 (+64).
//   Bank group = byte bits 4-6 ("slot", 8 x 16B slots per 128B row). Unswizzled,
//   16 lanes share each slot -> 16 acc/bank over banks 0-15 only (2x minimum).
//   Full-rank fix: slot ^= (row & 7). Read: byte ^= (fr&7)<<4. Coverage: for each
//   kg, fr=0..15 spreads over all 8 slots (2 lanes each) -> 8 acc/bank on all 32
//   banks = the 8-cycle wave64-b128 minimum (conflict-free).
//   Staging (global_load_lds writes linearly; rule #21 -> inverse-swizzle SOURCE):
//   dest row = tid>>3 (+64: same mod 8), dest slot = tid&7, so source col slot =
//   (tid&7) ^ ((tid>>3)&7).
//
// Per K-tile t (4 phases, ds_reads {12,8,4,0}):
//  q0: RD Aa(8)+B01(4); STAGE B(t+1,h0); bar; lgkm0; MFMA acc[0-3][0-1]; bar
//  q1: RD Ab(8);        STAGE B(t+1,h1); bar; lgkm0; MFMA acc[4-7][0-1]; bar
//  q2: RD B23(4);       STAGE A(t+2,h0); bar; lgkm0; MFMA acc[4-7][2-3]; bar
//  q3: (reuse Aa,B23);  STAGE A(t+2,h1); bar; lgkm0; MFMA acc[0-3][2-3]; vmcnt(4); bar
// Race-safety: A halves of buf[t&1] last ds_read at q1 -> A staging at q2/q3 OK.
// B staging targets buf[(t+1)&1], last read at (t-1).q2 -> q0/q1 OK.
// vmcnt(4): newest 4 in-flight loads are t+2's A -> everything <= B(t+1,h1) landed.

#define PH_MID() do { asm volatile("" ::: "memory"); __builtin_amdgcn_s_barrier(); \
    asm volatile("s_waitcnt lgkmcnt(0)" ::: "memory"); \
    __builtin_amdgcn_sched_barrier(0); __builtin_amdgcn_s_setprio(1); } while (0)

#define PH_END() do { __builtin_amdgcn_s_setprio(0); \
    asm volatile("" ::: "memory"); __builtin_amdgcn_s_barrier(); } while (0)

#define STG_A(s, h) { char* d_ = Al + (((s) & 1) << 15) + ((h) << 14); \
    const char* g_ = Ag + (long)(h) * 262144 + (s) * 128; \
    gload16(d_, g_); gload16(d_ + 8192, g_ + 131072); }

#define STG_B(s, h) { char* d_ = Bl + (((s) & 1) << 15) + ((h) << 14); \
    const char* g_ = Bg + (long)(h) * 262144 + (s) * 128; \
    gload16(d_, g_); gload16(d_ + 8192, g_ + 131072); }

#define RD_A(arr, c) { _Pragma("unroll") for (int mi_ = 0; mi_ < 4; ++mi_) { \
    const char* p_ = Ahalf + (((c) * 64 + mi_ * 16 + fr) << 7); \
    arr[mi_][0] = *(const bf16x8*)(p_ + cb0); \
    arr[mi_][1] = *(const bf16x8*)(p_ + cb1); } }

#define RD_B(g) { _Pragma("unroll") for (int nj_ = 0; nj_ < 2; ++nj_) { \
    const char* p_ = Bhalf + ((brow0 + (g) * 32 + nj_ * 16 + fr) << 7); \
    b[nj_][0] = *(const bf16x8*)(p_ + cb0); \
    b[nj_][1] = *(const bf16x8*)(p_ + cb1); } }

#define MM_Q(arr, c, g) { _Pragma("unroll") for (int mi_ = 0; mi_ < 4; ++mi_) { \
    _Pragma("unroll") for (int nj_ = 0; nj_ < 2; ++nj_) { \
      acc[(c)*4+mi_][(g)*2+nj_] = __builtin_amdgcn_mfma_f32_16x16x32_bf16( \
          arr[mi_][0], b[nj_][0], acc[(c)*4+mi_][(g)*2+nj_], 0, 0, 0); \
      acc[(c)*4+mi_][(g)*2+nj_] = __builtin_amdgcn_mfma_f32_16x16x32_bf16( \
          arr[mi_][1], b[nj_][1], acc[(c)*4+mi_][(g)*2+nj_], 0, 0, 0); } } }

__global__ __launch_bounds__(512, 2) void gemm_kernel(const __bf16* __restrict__ A,
                                                      const __bf16* __restrict__ B,
                                                      __bf16* __restrict__ Y, long r0) {
  __shared__ __align__(16) __bf16 As[2 * 2 * 8192];   // [buf][half][128][64] swizzled
  __shared__ __align__(16) __bf16 Bs[2 * 2 * 8192];

  const int tid  = threadIdx.x;
  const int lane = tid & 63;
  const int wid  = tid >> 6;        // 0..7
  const int wr   = wid >> 2;        // 0..1  (M half)
  const int wc   = wid & 3;         // 0..3  (N quarter)

  // bijective XCD-aware swizzle (m204)
  const int nwg = gridDim.x;
  const int q8 = nwg >> 3, r8 = nwg & 7;
  const int xcd = blockIdx.x & 7, rest = blockIdx.x >> 3;
  const int wgid = (xcd < r8 ? xcd * (q8 + 1) : r8 * (q8 + 1) + (xcd - r8) * q8) + rest;
  const long m0 = (long)(wgid >> 4) * 256;   // chunk-local row tile
  const long n0 = (long)(wgid & 15) * 256;

  // staging: linear dest (row=tid/8, slot=tid&7); inverse-swizzled global source:
  // source col slot = (tid&7) ^ ((tid>>3)&7). (+64-row half: row mod 8 unchanged.)
  const int scol = (((tid & 7) ^ ((tid >> 3) & 7)) << 4);
  const char* Ag = (const char*)(A + (r0 + m0) * KDIM) + (long)(tid >> 3) * 2048 + scol;
  const char* Bg = (const char*)(B + n0 * KDIM) + (long)(tid >> 3) * 2048 + scol;
  char* Al = (char*)As + tid * 16;
  char* Bl = (char*)Bs + tid * 16;

  // fragment read addressing: byte = row*128 + (slot<<4), slot ^= (row&7) = (fr&7)
  const int fr  = lane & 15;
  const int sw  = (fr & 7) << 4;
  const int cb0 = (((lane >> 4) << 4)) ^ sw;
  const int cb1 = (64 | ((lane >> 4) << 4)) ^ sw;
  const int brow0 = (wc & 1) << 6;

  f32x4 acc[8][4];
  const f32x4 z = {0.f, 0.f, 0.f, 0.f};
#pragma unroll
  for (int i = 0; i < 8; ++i)
#pragma unroll
    for (int j = 0; j < 4; ++j) acc[i][j] = z;

  // ---- prologue: 6 half-tiles (tile0 complete + tile1 A halves), per-wave 12 loads
  STG_A(0, 0); STG_A(0, 1); STG_B(0, 0); STG_B(0, 1); STG_A(1, 0); STG_A(1, 1);
  asm volatile("s_waitcnt vmcnt(4)" ::: "memory");   // tile0 fully landed
  __builtin_amdgcn_s_barrier();

  bf16x8 aa[4][2], ab[4][2], b[2][2];

#pragma unroll 2
  for (int t = 0; t < 16; ++t) {
    const char* Ahalf = (const char*)As + ((t & 1) << 15) + (wr << 14);
    const char* Bhalf = (const char*)Bs + ((t & 1) << 15) + ((wc >> 1) << 14);

    // q0
    RD_A(aa, 0); RD_B(0);
    if (t + 1 < 16) STG_B(t + 1, 0);
    PH_MID(); MM_Q(aa, 0, 0); PH_END();
    // q1
    RD_A(ab, 1);
    if (t + 1 < 16) STG_B(t + 1, 1);
    PH_MID(); MM_Q(ab, 1, 0); PH_END();
    // q2
    RD_B(1);
    if (t + 2 < 16) STG_A(t + 2, 0);
    PH_MID(); MM_Q(ab, 1, 1); PH_END();
    // q3 (reuse aa + b23)
    if (t + 2 < 16) STG_A(t + 2, 1);
    PH_MID(); MM_Q(aa, 0, 1);
    __builtin_amdgcn_s_setprio(0);
    if (t == 14)      { asm volatile("s_waitcnt vmcnt(0)" ::: "memory"); }
    else if (t < 14)  { asm volatile("s_waitcnt vmcnt(4)" ::: "memory"); }
    asm volatile("" ::: "memory");
    __builtin_amdgcn_s_barrier();
  }

  // ---- epilogue: C/D layout col=lane&15, row=(lane>>4)*4+reg
  const long mrow = m0 + wr * 128 + ((lane >> 4) << 2);
  const long ncol = n0 + wc * 64 + fr;
  __bf16* Yp = Y + mrow * NCOLS + ncol;
#pragma unroll
  for (int c = 0; c < 2; ++c)
#pragma unroll
    for (int mi = 0; mi < 4; ++mi)
#pragma unroll
      for (int nj = 0; nj < 4; ++nj)
#pragma unroll
        for (int r = 0; r < 4; ++r)
          Yp[(long)(c * 64 + mi * 16 + r) * NCOLS + nj * 16] = (__bf16)acc[c * 4 + mi][nj][r];
}

// ---------------- pass 2: row LN + gates + cell LN + output ----------------
__global__ __launch_bounds__(256) void pass2_kernel(const __bf16* __restrict__ Yw,
                                                    const float* __restrict__ bi,
                                                    const float* __restrict__ g_i2h,
                                                    const float* __restrict__ g_cell,
                                                    const float* __restrict__ b_cell,
                                                    float* __restrict__ out, long r0) {
  __shared__ float p0[4096];
  __shared__ float red[8];
  const int tid  = threadIdx.x;
  const long row = r0 + blockIdx.x;           // global row (t*64 + b)
  const bf16x8* yv = (const bf16x8*)(Yw + (long)blockIdx.x * NCOLS);

  // phase 1: p = y + bi (fp32), stash in LDS, accumulate stats over 4096
  float s = 0.f, ss = 0.f;
#pragma unroll
  for (int it = 0; it < 2; ++it) {
    const int ch = tid + it * 256;            // 8-elem chunk id, 0..511
    const bf16x8 v = yv[ch];
    const float4 b0 = ((const float4*)bi)[ch * 2];
    const float4 b1 = ((const float4*)bi)[ch * 2 + 1];
    float p[8];
    p[0] = (float)v[0] + b0.x;  p[1] = (float)v[1] + b0.y;
    p[2] = (float)v[2] + b0.z;  p[3] = (float)v[3] + b0.w;
    p[4] = (float)v[4] + b1.x;  p[5] = (float)v[5] + b1.y;
    p[6] = (float)v[6] + b1.z;  p[7] = (float)v[7] + b1.w;
#pragma unroll
    for (int u = 0; u < 8; ++u) {
      p0[ch * 8 + u] = p[u];
      s += p[u];
      ss += p[u] * p[u];
    }
  }
  block_reduce2(s, ss, red, tid);             // also fences p0 writes
  const float mu  = s * (1.f / 4096.f);
  const float var = (ss - 4096.f * mu * mu) * (1.f / 4095.f);   // ddof=1
  const float rs  = rsqrtf(var + 1e-6f);

  // phase 2: gates + cell accumulation (j = tid + u*256)
  float cc[4], oo[4];
  float s2 = 0.f, ss2 = 0.f;
#pragma unroll
  for (int u = 0; u < 4; ++u) {
    const int j = tid + u * 256;
    const float pf = g_i2h[1024 + j] * ((p0[1024 + j] - mu) * rs) + g_Cvec[1024 + j];
    const float po = g_i2h[2048 + j] * ((p0[2048 + j] - mu) * rs) + g_Cvec[2048 + j];
    const float pg = g_i2h[3072 + j] * ((p0[3072 + j] - mu) * rs) + g_Cvec[3072 + j];
    const float f  = 1.f / (1.f + __expf(-pf));
    oo[u] = 1.f / (1.f + __expf(-po));
    const float e2 = __expf(2.f * pg);
    const float gt = (e2 - 1.f) / (e2 + 1.f);   // tanh
    cc[u] = (1.f - f) * gt;                     // c0 = 0
    s2 += cc[u]; ss2 += cc[u] * cc[u];
  }
  block_reduce2(s2, ss2, red, tid);
  const float mu2  = s2 * (1.f / 1024.f);
  const float var2 = (ss2 - 1024.f * mu2 * mu2) * (1.f / 1023.f);  // ddof=1
  const float rs2  = rsqrtf(var2 + 1e-6f);

  const long obase = row * 1024;
#pragma unroll
  for (int u = 0; u < 4; ++u) {
    const int j = tid + u * 256;
    const float cn = g_cell[j] * ((cc[u] - mu2) * rs2) + b_cell[j];
    const float e2 = __expf(2.f * cn);
    const float th = (e2 - 1.f) / (e2 + 1.f);
    const float h  = oo[u] * th;
    out[obase + j] = h;
    if (row >= MROWS - 64)                       // t == T-1
      out[MROWS * 1024 + ((row - (MROWS - 64)) << 10) + j] = h;
  }
}

extern "C" void kernel_launch(void* const* d_in, const int* in_sizes, int n_in,
                              void* d_out, int out_size, void* d_ws, size_t ws_size,
                              hipStream_t stream) {
  (void)in_sizes; (void)n_in; (void)out_size;
  const float* x      = (const float*)d_in[0];
  const float* Wi     = (const float*)d_in[1];
  const float* bi     = (const float*)d_in[2];
  // d_in[3] = Wh : unused (h0 == 0)
  const float* bh     = (const float*)d_in[4];
  const float* g_i2h  = (const float*)d_in[5];
  const float* b_i2h  = (const float*)d_in[6];
  const float* g_h2h  = (const float*)d_in[7];
  const float* b_h2h  = (const float*)d_in[8];
  const float* g_cell = (const float*)d_in[9];
  const float* b_cell = (const float*)d_in[10];
  float* out = (float*)d_out;

  // Scratch carved from d_out (fully overwritten by pass2 afterwards):
  //   [0, 64MB)    x as bf16
  //   [64MB, 72MB) Wi as bf16
  __bf16* xb = (__bf16*)d_out;
  __bf16* wb = (__bf16*)((char*)d_out + 67108864);
  __bf16* y  = (__bf16*)d_ws;   // Y intermediate, up to 256 MB (chunked if ws smaller)

  cast_kernel<<<2048, 256, 0, stream>>>((const float4*)x, (bf16x4*)xb, 33554432 / 4);
  cast_kernel<<<1024, 256, 0, stream>>>((const float4*)Wi, (bf16x4*)wb, 4194304 / 4);
  prep_kernel<<<1, 256, 0, stream>>>(bh, b_i2h, g_h2h, b_h2h);

  // chunk over M if the workspace can't hold the full 32768x4096 bf16 Y
  long max_rows = (long)(ws_size / (NCOLS * 2)) & ~255L;
  if (max_rows > MROWS) max_rows = MROWS;
  if (max_rows < 256)   max_rows = 256;   // assume ws >= 2 MB
  for (long rbase = 0; rbase < MROWS; rbase += max_rows) {
    const long rows = (MROWS - rbase < max_rows) ? (MROWS - rbase) : max_rows;
    gemm_kernel<<<dim3((rows / 256) * 16), 512, 0, stream>>>(xb, wb, y, rbase);
    pass2_kernel<<<dim3(rows), 256, 0, stream>>>(y, bi, g_i2h, g_cell, b_cell, out, rbase);
  }
}

// Round 5
// 431.859 us; speedup vs baseline: 1.1888x; 1.1271x over previous
//
#include <hip/hip_runtime.h>
#include <hip/hip_bf16.h>
#include <stdint.h>

// LayerNormLSTM: T=512, B=64, I=1024, H=1024
// M = T*B = 32768 rows, N = 4*H = 4096, K = 1024.
// Reference degenerates (h0=c0=0, no scan):
//   h2h_vec = LN(bh; g_h2h, b_h2h)            (constant 4096-vec; Wh unused)
//   y       = x @ Wi^T                         (big GEMM)
//   p       = g_i2h * LNrow(y + bi) + (b_i2h + h2h_vec)
//   f,o     = sigmoid(p[H:2H]), sigmoid(p[2H:3H]); g = tanh(p[3H:])
//   c       = (1-f)*g ;  cn = LN_H(c) ;  h = o * tanh(cn)
// out = [h (T,B,H) ; h[-1] (B,H)]
//
// Scratch ledger (R4 post-mortem: NEVER carve scratch from d_out with
// multi-chunk pass2 — pass2's out-writes destroyed xb rows chunk k+1 needed):
//   d_ws: [0,64MB) xb | [64MB,72MB) wb | [72MB, 72MB+chunk) Y
//   d_out: written only by pass2 (final output).

#define MROWS 32768L
#define NCOLS 4096
#define KDIM  1024

typedef __bf16 bf16x8 __attribute__((ext_vector_type(8)));
typedef __bf16 bf16x4 __attribute__((ext_vector_type(4)));
typedef float  f32x4  __attribute__((ext_vector_type(4)));

__device__ float g_Cvec[4096];   // b_i2h + h2h_vec (recomputed every launch)

__device__ __forceinline__ void gload16(char* lds, const char* g) {
  __builtin_amdgcn_global_load_lds(
      (const __attribute__((address_space(1))) char*)g,
      (__attribute__((address_space(3))) char*)lds, 16, 0, 0);
}

__device__ __forceinline__ void block_reduce2(float& a, float& b, float* red, int tid) {
#pragma unroll
  for (int m = 32; m > 0; m >>= 1) {
    a += __shfl_xor(a, m, 64);
    b += __shfl_xor(b, m, 64);
  }
  const int lane = tid & 63, wid = tid >> 6;
  if (lane == 0) { red[wid] = a; red[4 + wid] = b; }
  __syncthreads();
  a = red[0] + red[1] + red[2] + red[3];
  b = red[4] + red[5] + red[6] + red[7];
  __syncthreads();  // safe reuse of red[]
}

// ---------------- cast f32 -> bf16 (vectorized) ----------------
__global__ __launch_bounds__(256) void cast_kernel(const float4* __restrict__ in,
                                                   bf16x4* __restrict__ out, int n4) {
  int i = blockIdx.x * 256 + threadIdx.x;
  const int stride = gridDim.x * 256;
  for (; i < n4; i += stride) {
    const float4 v = in[i];
    bf16x4 o = { (__bf16)v.x, (__bf16)v.y, (__bf16)v.z, (__bf16)v.w };
    out[i] = o;
  }
}

// ---------------- prep: Cvec = b_i2h + LN(bh)*g_h2h + b_h2h ----------------
__global__ __launch_bounds__(256) void prep_kernel(const float* __restrict__ bh,
                                                   const float* __restrict__ b_i2h,
                                                   const float* __restrict__ g_h2h,
                                                   const float* __restrict__ b_h2h) {
  __shared__ float red[8];
  const int tid = threadIdx.x;
  float v[16];
  float s = 0.f, ss = 0.f;
#pragma unroll
  for (int u = 0; u < 16; ++u) {
    v[u] = bh[tid + u * 256];
    s += v[u]; ss += v[u] * v[u];
  }
  block_reduce2(s, ss, red, tid);
  const float mu  = s * (1.f / 4096.f);
  const float var = (ss - 4096.f * mu * mu) * (1.f / 4095.f);   // ddof=1
  const float rs  = rsqrtf(var + 1e-6f);
#pragma unroll
  for (int u = 0; u < 16; ++u) {
    const int g = tid + u * 256;
    g_Cvec[g] = b_i2h[g] + g_h2h[g] * ((v[u] - mu) * rs) + b_h2h[g];
  }
}

// ---------------- GEMM: Y[m][n] = sum_k A[m][k]*B[n][k]  (bf16 in, bf16 out) ----
// 256x256x64 tile, 8 waves (2Mx4N), 128KiB LDS [2 dbuf][2 half][128][64],
// full-rank LDS swizzle (R3: slot ^= row&7, conflicts measured 0).
//
// Software-pipelined register loads (reads one phase ahead, ping-pong reg
// sets), 4 barriers/tile, counted vmcnt. Phase body:
//   [lgkmcnt(0); sched_barrier]  <- waits reads issued LAST phase (hidden)
//   [issue next phase's ds_reads] [MFMA on current regs] [staging] [barrier]
//
// Staging schedule (per tile t):   Reg schedule:
//   q0: STG B(t+1,h1)               q0: RD Ab(t)   -> An
//   q2: STG A(t+2,h0); vmcnt; bar   q1: RD B23(t)  -> Bn
//   q3: STG A(t+2,h1), B(t+2,h0)    q3: RD Aa(t+1) -> An, B01(t+1) -> Bc
// MFMA: q0: Ac*Bc (acc[0-3][0-1]) q1: An*Bc ([4-7][0-1])
//       q2: An*Bn ([4-7][2-3])    q3: Ac*Bn ([0-3][2-3])
// A-sets swap roles each tile; B01 slot (Bc) and B23 slot (Bn) are fixed.
//
// Safety ledger:
//  - buf[t+1] valid before q3 pre-reads: per-wave vmcnt(2) at q2 leaves only
//    A(t+2,h0) in flight -> B(t+1,h1) (issued t.q0) + all older landed; q2's
//    barrier makes that hold for ALL waves before any wave reaches q3.
//  - overwrite-vs-reader: A(t,h0) read at t-1.q3, done by q0's lgkm0 (< q0
//    bar); overwritten t.q2 (2 bars later). A(t,h1) done by q1's lgkm0;
//    overwritten t.q3. B(t,h0) done by q0; overwritten t.q3. B(t,h1) done by
//    q2's lgkm0; overwritten t+1.q0. All >=1 barrier separation.
//  - q3 pre-reads target buf[(t+1)&1]; q3 STGs write buf[t&1]: disjoint.
//  - tails: t=14 q2 -> vmcnt(0) (covers B(15,h1)); t=15 stages/pre-reads none.

#define LGKM0() do { asm volatile("s_waitcnt lgkmcnt(0)" ::: "memory"); \
    __builtin_amdgcn_sched_barrier(0); } while (0)
#define BAR()   do { asm volatile("" ::: "memory"); __builtin_amdgcn_s_barrier(); \
    asm volatile("" ::: "memory"); } while (0)
#define VMCNT(n) asm volatile("s_waitcnt vmcnt(" #n ")" ::: "memory")

#define STG_A(s, h) { char* d_ = Al + (((s) & 1) << 15) + ((h) << 14); \
    const char* g_ = Ag + (long)(h) * 262144 + (s) * 128; \
    gload16(d_, g_); gload16(d_ + 8192, g_ + 131072); }

#define STG_B(s, h) { char* d_ = Bl + (((s) & 1) << 15) + ((h) << 14); \
    const char* g_ = Bg + (long)(h) * 262144 + (s) * 128; \
    gload16(d_, g_); gload16(d_ + 8192, g_ + 131072); }

#define ABASE(t) ((const char*)As + (((t) & 1) << 15) + (wr << 14))
#define BBASE(t) ((const char*)Bs + (((t) & 1) << 15) + ((wc >> 1) << 14))

#define RD_Ax(arr, Ahalf, c) { _Pragma("unroll") for (int mi_ = 0; mi_ < 4; ++mi_) { \
    const char* p_ = (Ahalf) + (((c) * 64 + mi_ * 16 + fr) << 7); \
    arr[mi_][0] = *(const bf16x8*)(p_ + cb0); \
    arr[mi_][1] = *(const bf16x8*)(p_ + cb1); } }

#define RD_Bx(arr, Bhalf, g) { _Pragma("unroll") for (int nj_ = 0; nj_ < 2; ++nj_) { \
    const char* p_ = (Bhalf) + ((brow0 + (g) * 32 + nj_ * 16 + fr) << 7); \
    arr[nj_][0] = *(const bf16x8*)(p_ + cb0); \
    arr[nj_][1] = *(const bf16x8*)(p_ + cb1); } }

#define MMQ(X, Y, c, g) { _Pragma("unroll") for (int mi_ = 0; mi_ < 4; ++mi_) { \
    _Pragma("unroll") for (int nj_ = 0; nj_ < 2; ++nj_) { \
      acc[(c)*4+mi_][(g)*2+nj_] = __builtin_amdgcn_mfma_f32_16x16x32_bf16( \
          X[mi_][0], Y[nj_][0], acc[(c)*4+mi_][(g)*2+nj_], 0, 0, 0); \
      acc[(c)*4+mi_][(g)*2+nj_] = __builtin_amdgcn_mfma_f32_16x16x32_bf16( \
          X[mi_][1], Y[nj_][1], acc[(c)*4+mi_][(g)*2+nj_], 0, 0, 0); } } }

#define SETP1() __builtin_amdgcn_s_setprio(1)
#define SETP0() __builtin_amdgcn_s_setprio(0)

// G1 = (t+1 < 16), G2 = (t+2 < 16) as compile-time literals.
#define TILE(t, Ac, An, Bc, Bn, G1, G2) { \
    const char* AhC = ABASE(t); const char* BhC = BBASE(t); \
    const char* AhN = ABASE((t) + 1); const char* BhN = BBASE((t) + 1); \
    /* q0 */ LGKM0(); RD_Ax(An, AhC, 1); if (G1) STG_B((t) + 1, 1); \
    SETP1(); MMQ(Ac, Bc, 0, 0); SETP0(); BAR(); \
    /* q1 */ LGKM0(); RD_Bx(Bn, BhC, 1); \
    SETP1(); MMQ(An, Bc, 1, 0); SETP0(); BAR(); \
    /* q2 */ LGKM0(); if (G2) STG_A((t) + 2, 0); \
    SETP1(); MMQ(An, Bn, 1, 1); SETP0(); \
    if (G2) { VMCNT(2); } else { VMCNT(0); } BAR(); \
    /* q3 */ if (G1) { RD_Ax(An, AhN, 0); RD_Bx(Bc, BhN, 0); } \
    if (G2) { STG_A((t) + 2, 1); STG_B((t) + 2, 0); } \
    SETP1(); MMQ(Ac, Bn, 0, 1); SETP0(); BAR(); }

__global__ __launch_bounds__(512, 2) void gemm_kernel(const __bf16* __restrict__ A,
                                                      const __bf16* __restrict__ B,
                                                      __bf16* __restrict__ Y, long r0) {
  __shared__ __align__(16) __bf16 As[2 * 2 * 8192];   // [buf][half][128][64] swizzled
  __shared__ __align__(16) __bf16 Bs[2 * 2 * 8192];

  const int tid  = threadIdx.x;
  const int lane = tid & 63;
  const int wid  = tid >> 6;        // 0..7
  const int wr   = wid >> 2;        // 0..1  (M half)
  const int wc   = wid & 3;         // 0..3  (N quarter)

  // bijective XCD-aware swizzle (m204)
  const int nwg = gridDim.x;
  const int q8 = nwg >> 3, r8 = nwg & 7;
  const int xcd = blockIdx.x & 7, rest = blockIdx.x >> 3;
  const int wgid = (xcd < r8 ? xcd * (q8 + 1) : r8 * (q8 + 1) + (xcd - r8) * q8) + rest;
  const long m0 = (long)(wgid >> 4) * 256;   // chunk-local row tile
  const long n0 = (long)(wgid & 15) * 256;

  // staging: linear dest (row=tid/8, slot=tid&7); inverse-swizzled global source:
  // source col slot = (tid&7) ^ ((tid>>3)&7). (+64-row half: row mod 8 unchanged.)
  const int scol = (((tid & 7) ^ ((tid >> 3) & 7)) << 4);
  const char* Ag = (const char*)(A + (r0 + m0) * KDIM) + (long)(tid >> 3) * 2048 + scol;
  const char* Bg = (const char*)(B + n0 * KDIM) + (long)(tid >> 3) * 2048 + scol;
  char* Al = (char*)As + tid * 16;
  char* Bl = (char*)Bs + tid * 16;

  // fragment read addressing: byte = row*128 + (slot<<4), slot ^= (row&7) = (fr&7)
  const int fr  = lane & 15;
  const int sw  = (fr & 7) << 4;
  const int cb0 = (((lane >> 4) << 4)) ^ sw;
  const int cb1 = (64 | ((lane >> 4) << 4)) ^ sw;
  const int brow0 = (wc & 1) << 6;

  f32x4 acc[8][4];
  const f32x4 z = {0.f, 0.f, 0.f, 0.f};
#pragma unroll
  for (int i = 0; i < 8; ++i)
#pragma unroll
    for (int j = 0; j < 4; ++j) acc[i][j] = z;

  bf16x8 A0[4][2], A1[4][2], B0[2][2], B1[2][2];

  // ---- prologue: buf0 full + A(1) + B(1,h0) = 14 loads; wait the 8 oldest.
  STG_A(0, 0); STG_A(0, 1); STG_B(0, 0); STG_B(0, 1);
  STG_A(1, 0); STG_A(1, 1); STG_B(1, 0);
  VMCNT(6);
  BAR();
  RD_Ax(A0, ABASE(0), 0); RD_Bx(B0, BBASE(0), 0);   // q0(0) pre-reads

#pragma unroll 1
  for (int tt = 0; tt < 7; ++tt) {
    const int t = tt * 2;
    TILE(t,     A0, A1, B0, B1, true, true);
    TILE(t + 1, A1, A0, B0, B1, true, true);
  }
  TILE(14, A0, A1, B0, B1, true,  false);
  TILE(15, A1, A0, B0, B1, false, false);

  // ---- epilogue: C/D layout col=lane&15, row=(lane>>4)*4+reg
  const long mrow = m0 + wr * 128 + ((lane >> 4) << 2);
  const long ncol = n0 + wc * 64 + fr;
  __bf16* Yp = Y + mrow * NCOLS + ncol;
#pragma unroll
  for (int c = 0; c < 2; ++c)
#pragma unroll
    for (int mi = 0; mi < 4; ++mi)
#pragma unroll
      for (int nj = 0; nj < 4; ++nj)
#pragma unroll
        for (int r = 0; r < 4; ++r)
          Yp[(long)(c * 64 + mi * 16 + r) * NCOLS + nj * 16] = (__bf16)acc[c * 4 + mi][nj][r];
}

// ---------------- pass 2: row LN + gates + cell LN + output ----------------
__global__ __launch_bounds__(256) void pass2_kernel(const __bf16* __restrict__ Yw,
                                                    const float* __restrict__ bi,
                                                    const float* __restrict__ g_i2h,
                                                    const float* __restrict__ g_cell,
                                                    const float* __restrict__ b_cell,
                                                    float* __restrict__ out, long r0) {
  __shared__ float p0[4096];
  __shared__ float red[8];
  const int tid  = threadIdx.x;
  const long row = r0 + blockIdx.x;           // global row (t*64 + b)
  const bf16x8* yv = (const bf16x8*)(Yw + (long)blockIdx.x * NCOLS);

  // phase 1: p = y + bi (fp32), stash in LDS, accumulate stats over 4096
  float s = 0.f, ss = 0.f;
#pragma unroll
  for (int it = 0; it < 2; ++it) {
    const int ch = tid + it * 256;            // 8-elem chunk id, 0..511
    const bf16x8 v = yv[ch];
    const float4 b0 = ((const float4*)bi)[ch * 2];
    const float4 b1 = ((const float4*)bi)[ch * 2 + 1];
    float p[8];
    p[0] = (float)v[0] + b0.x;  p[1] = (float)v[1] + b0.y;
    p[2] = (float)v[2] + b0.z;  p[3] = (float)v[3] + b0.w;
    p[4] = (float)v[4] + b1.x;  p[5] = (float)v[5] + b1.y;
    p[6] = (float)v[6] + b1.z;  p[7] = (float)v[7] + b1.w;
#pragma unroll
    for (int u = 0; u < 8; ++u) {
      p0[ch * 8 + u] = p[u];
      s += p[u];
      ss += p[u] * p[u];
    }
  }
  block_reduce2(s, ss, red, tid);             // also fences p0 writes
  const float mu  = s * (1.f / 4096.f);
  const float var = (ss - 4096.f * mu * mu) * (1.f / 4095.f);   // ddof=1
  const float rs  = rsqrtf(var + 1e-6f);

  // phase 2: gates + cell accumulation (j = tid + u*256)
  float cc[4], oo[4];
  float s2 = 0.f, ss2 = 0.f;
#pragma unroll
  for (int u = 0; u < 4; ++u) {
    const int j = tid + u * 256;
    const float pf = g_i2h[1024 + j] * ((p0[1024 + j] - mu) * rs) + g_Cvec[1024 + j];
    const float po = g_i2h[2048 + j] * ((p0[2048 + j] - mu) * rs) + g_Cvec[2048 + j];
    const float pg = g_i2h[3072 + j] * ((p0[3072 + j] - mu) * rs) + g_Cvec[3072 + j];
    const float f  = 1.f / (1.f + __expf(-pf));
    oo[u] = 1.f / (1.f + __expf(-po));
    const float e2 = __expf(2.f * pg);
    const float gt = (e2 - 1.f) / (e2 + 1.f);   // tanh
    cc[u] = (1.f - f) * gt;                     // c0 = 0
    s2 += cc[u]; ss2 += cc[u] * cc[u];
  }
  block_reduce2(s2, ss2, red, tid);
  const float mu2  = s2 * (1.f / 1024.f);
  const float var2 = (ss2 - 1024.f * mu2 * mu2) * (1.f / 1023.f);  // ddof=1
  const float rs2  = rsqrtf(var2 + 1e-6f);

  const long obase = row * 1024;
#pragma unroll
  for (int u = 0; u < 4; ++u) {
    const int j = tid + u * 256;
    const float cn = g_cell[j] * ((cc[u] - mu2) * rs2) + b_cell[j];
    const float e2 = __expf(2.f * cn);
    const float th = (e2 - 1.f) / (e2 + 1.f);
    const float h  = oo[u] * th;
    out[obase + j] = h;
    if (row >= MROWS - 64)                       // t == T-1
      out[MROWS * 1024 + ((row - (MROWS - 64)) << 10) + j] = h;
  }
}

extern "C" void kernel_launch(void* const* d_in, const int* in_sizes, int n_in,
                              void* d_out, int out_size, void* d_ws, size_t ws_size,
                              hipStream_t stream) {
  (void)in_sizes; (void)n_in; (void)out_size;
  const float* x      = (const float*)d_in[0];
  const float* Wi     = (const float*)d_in[1];
  const float* bi     = (const float*)d_in[2];
  // d_in[3] = Wh : unused (h0 == 0)
  const float* bh     = (const float*)d_in[4];
  const float* g_i2h  = (const float*)d_in[5];
  const float* b_i2h  = (const float*)d_in[6];
  const float* g_h2h  = (const float*)d_in[7];
  const float* b_h2h  = (const float*)d_in[8];
  const float* g_cell = (const float*)d_in[9];
  const float* b_cell = (const float*)d_in[10];
  float* out = (float*)d_out;

  // All scratch in d_ws (ws >= 256MB evidence: R1-R3 held full 256MB Y there):
  //   [0, 64MB)     xb : x as bf16
  //   [64MB, 72MB)  wb : Wi as bf16
  //   [72MB, ...)   y  : Y chunk (<= 64MB)
  __bf16* xb = (__bf16*)d_ws;
  __bf16* wb = (__bf16*)((char*)d_ws + 67108864);
  __bf16* y  = (__bf16*)((char*)d_ws + 75497472);

  cast_kernel<<<2048, 256, 0, stream>>>((const float4*)x, (bf16x4*)xb, 33554432 / 4);
  cast_kernel<<<1024, 256, 0, stream>>>((const float4*)Wi, (bf16x4*)wb, 4194304 / 4);
  prep_kernel<<<1, 256, 0, stream>>>(bh, b_i2h, g_h2h, b_h2h);

  // chunk over M: cap at 8192 rows (Y chunk = 64 MB) so pass2 re-reads Y from
  // L2/L3 instead of HBM; also bounded by remaining workspace.
  long avail = (long)ws_size - 75497472L;
  long max_rows = (avail / (NCOLS * 2)) & ~255L;
  if (max_rows > 8192) max_rows = 8192;
  if (max_rows < 256)  max_rows = 256;   // assume ws >= ~74 MB
  for (long rbase = 0; rbase < MROWS; rbase += max_rows) {
    const long rows = (MROWS - rbase < max_rows) ? (MROWS - rbase) : max_rows;
    gemm_kernel<<<dim3((rows / 256) * 16), 512, 0, stream>>>(xb, wb, y, rbase);
    pass2_kernel<<<dim3(rows), 256, 0, stream>>>(y, bi, g_i2h, g_cell, b_cell, out, rbase);
  }
}

// Round 6
// 428.435 us; speedup vs baseline: 1.1983x; 1.0080x over previous
//
#include <hip/hip_runtime.h>
#include <hip/hip_bf16.h>
#include <stdint.h>

// LayerNormLSTM: T=512, B=64, I=1024, H=1024
// M = T*B = 32768 rows, N = 4*H = 4096, K = 1024.
// Reference degenerates (h0=c0=0, no scan):
//   h2h_vec = LN(bh; g_h2h, b_h2h)            (constant 4096-vec; Wh unused)
//   y       = x @ Wi^T                         (big GEMM)
//   p       = g_i2h * LNrow(y + bi) + (b_i2h + h2h_vec)
//   f,o     = sigmoid(p[H:2H]), sigmoid(p[2H:3H]); g = tanh(p[3H:])
//   c       = (1-f)*g ;  cn = LN_H(c) ;  h = o * tanh(cn)
// out = [h (T,B,H) ; h[-1] (B,H)]
//
// Scratch ledger (R4 post-mortem: NEVER carve scratch from d_out with
// multi-chunk pass2):  d_ws: [0,64MB) xb | [64MB,72MB) wb | [72MB,+64MB) Y
//
// R6: BARE s_barrier (no asm-"memory" wrappers). R2/R3/R5 all ran at the
// same 6280 cyc/tile (= the guide's drain0/1-phase level) despite three
// different schedules; the shared detail was memory-clobber fences around
// every barrier, which defeat counted-vmcnt by forcing drains. The
// s_waitcnt asms (with "memory") remain the ordering fences.

#define MROWS 32768L
#define NCOLS 4096
#define KDIM  1024

typedef __bf16 bf16x8 __attribute__((ext_vector_type(8)));
typedef __bf16 bf16x4 __attribute__((ext_vector_type(4)));
typedef float  f32x4  __attribute__((ext_vector_type(4)));

__device__ float g_Cvec[4096];   // b_i2h + h2h_vec (recomputed every launch)

__device__ __forceinline__ void gload16(char* lds, const char* g) {
  __builtin_amdgcn_global_load_lds(
      (const __attribute__((address_space(1))) char*)g,
      (__attribute__((address_space(3))) char*)lds, 16, 0, 0);
}

__device__ __forceinline__ void block_reduce2(float& a, float& b, float* red, int tid) {
#pragma unroll
  for (int m = 32; m > 0; m >>= 1) {
    a += __shfl_xor(a, m, 64);
    b += __shfl_xor(b, m, 64);
  }
  const int lane = tid & 63, wid = tid >> 6;
  if (lane == 0) { red[wid] = a; red[4 + wid] = b; }
  __syncthreads();
  a = red[0] + red[1] + red[2] + red[3];
  b = red[4] + red[5] + red[6] + red[7];
  __syncthreads();  // safe reuse of red[]
}

// ---------------- cast f32 -> bf16 (vectorized) ----------------
__global__ __launch_bounds__(256) void cast_kernel(const float4* __restrict__ in,
                                                   bf16x4* __restrict__ out, int n4) {
  int i = blockIdx.x * 256 + threadIdx.x;
  const int stride = gridDim.x * 256;
  for (; i < n4; i += stride) {
    const float4 v = in[i];
    bf16x4 o = { (__bf16)v.x, (__bf16)v.y, (__bf16)v.z, (__bf16)v.w };
    out[i] = o;
  }
}

// ---------------- prep: Cvec = b_i2h + LN(bh)*g_h2h + b_h2h ----------------
__global__ __launch_bounds__(256) void prep_kernel(const float* __restrict__ bh,
                                                   const float* __restrict__ b_i2h,
                                                   const float* __restrict__ g_h2h,
                                                   const float* __restrict__ b_h2h) {
  __shared__ float red[8];
  const int tid = threadIdx.x;
  float v[16];
  float s = 0.f, ss = 0.f;
#pragma unroll
  for (int u = 0; u < 16; ++u) {
    v[u] = bh[tid + u * 256];
    s += v[u]; ss += v[u] * v[u];
  }
  block_reduce2(s, ss, red, tid);
  const float mu  = s * (1.f / 4096.f);
  const float var = (ss - 4096.f * mu * mu) * (1.f / 4095.f);   // ddof=1
  const float rs  = rsqrtf(var + 1e-6f);
#pragma unroll
  for (int u = 0; u < 16; ++u) {
    const int g = tid + u * 256;
    g_Cvec[g] = b_i2h[g] + g_h2h[g] * ((v[u] - mu) * rs) + b_h2h[g];
  }
}

// ---------------- GEMM: Y[m][n] = sum_k A[m][k]*B[n][k]  (bf16 in, bf16 out) ----
// 256x256x64 tile, 8 waves (2Mx4N), 128KiB LDS [2 dbuf][2 half][128][64],
// full-rank LDS swizzle (slot ^= row&7; conflicts measured 0 in R3).
//
// Software-pipelined register loads (reads one phase ahead, ping-pong reg
// sets), 4 barriers/tile, counted vmcnt. Phase body:
//   [lgkmcnt(0); sched_barrier]  <- waits reads issued LAST phase (hidden)
//   [issue next phase's ds_reads] [MFMA on current regs] [staging] [barrier]
//
// Staging schedule (per tile t):   Reg schedule:
//   q0: STG B(t+1,h1)               q0: RD Ab(t)   -> An
//   q2: STG A(t+2,h0); vmcnt; bar   q1: RD B23(t)  -> Bn
//   q3: STG A(t+2,h1), B(t+2,h0)    q3: RD Aa(t+1) -> An, B01(t+1) -> Bc
// MFMA: q0: Ac*Bc (acc[0-3][0-1]) q1: An*Bc ([4-7][0-1])
//       q2: An*Bn ([4-7][2-3])    q3: Ac*Bn ([0-3][2-3])
// A-sets swap roles each tile; B01 slot (Bc) and B23 slot (Bn) are fixed.
//
// Safety ledger (all edges cross >=1 memory-clobber s_waitcnt asm + barrier):
//  - buf[t+1] valid before q3 pre-reads: per-wave vmcnt(2) at q2 leaves only
//    A(t+2,h0) in flight -> B(t+1,h1) (issued t.q0) + all older landed; q2's
//    barrier makes that hold for ALL waves before any wave reaches q3.
//  - overwrite-vs-reader: A(t,h0) read at t-1.q3, done by q0's lgkm0;
//    overwritten t.q2. A(t,h1) done q1; overwritten t.q3. B(t,h0) done q0;
//    overwritten t.q3. B(t,h1) done q2; overwritten t+1.q0.
//  - q3 pre-reads target buf[(t+1)&1]; q3 STGs write buf[t&1]: disjoint.
//  - tails: t=14 q2 -> vmcnt(0) (covers B(15,h1)); t=15 stages/pre-reads none.

#define LGKM0() do { asm volatile("s_waitcnt lgkmcnt(0)" ::: "memory"); \
    __builtin_amdgcn_sched_barrier(0); } while (0)
#define BAR()   __builtin_amdgcn_s_barrier()
#define VMCNT(n) asm volatile("s_waitcnt vmcnt(" #n ")" ::: "memory")

#define STG_A(s, h) { char* d_ = Al + (((s) & 1) << 15) + ((h) << 14); \
    const char* g_ = Ag + (long)(h) * 262144 + (s) * 128; \
    gload16(d_, g_); gload16(d_ + 8192, g_ + 131072); }

#define STG_B(s, h) { char* d_ = Bl + (((s) & 1) << 15) + ((h) << 14); \
    const char* g_ = Bg + (long)(h) * 262144 + (s) * 128; \
    gload16(d_, g_); gload16(d_ + 8192, g_ + 131072); }

#define ABASE(t) ((const char*)As + (((t) & 1) << 15) + (wr << 14))
#define BBASE(t) ((const char*)Bs + (((t) & 1) << 15) + ((wc >> 1) << 14))

#define RD_Ax(arr, Ahalf, c) { _Pragma("unroll") for (int mi_ = 0; mi_ < 4; ++mi_) { \
    const char* p_ = (Ahalf) + (((c) * 64 + mi_ * 16 + fr) << 7); \
    arr[mi_][0] = *(const bf16x8*)(p_ + cb0); \
    arr[mi_][1] = *(const bf16x8*)(p_ + cb1); } }

#define RD_Bx(arr, Bhalf, g) { _Pragma("unroll") for (int nj_ = 0; nj_ < 2; ++nj_) { \
    const char* p_ = (Bhalf) + ((brow0 + (g) * 32 + nj_ * 16 + fr) << 7); \
    arr[nj_][0] = *(const bf16x8*)(p_ + cb0); \
    arr[nj_][1] = *(const bf16x8*)(p_ + cb1); } }

#define MMQ(X, Y, c, g) { _Pragma("unroll") for (int mi_ = 0; mi_ < 4; ++mi_) { \
    _Pragma("unroll") for (int nj_ = 0; nj_ < 2; ++nj_) { \
      acc[(c)*4+mi_][(g)*2+nj_] = __builtin_amdgcn_mfma_f32_16x16x32_bf16( \
          X[mi_][0], Y[nj_][0], acc[(c)*4+mi_][(g)*2+nj_], 0, 0, 0); \
      acc[(c)*4+mi_][(g)*2+nj_] = __builtin_amdgcn_mfma_f32_16x16x32_bf16( \
          X[mi_][1], Y[nj_][1], acc[(c)*4+mi_][(g)*2+nj_], 0, 0, 0); } } }

#define SETP1() __builtin_amdgcn_s_setprio(1)
#define SETP0() __builtin_amdgcn_s_setprio(0)

// G1 = (t+1 < 16), G2 = (t+2 < 16) as compile-time literals.
#define TILE(t, Ac, An, Bc, Bn, G1, G2) { \
    const char* AhC = ABASE(t); const char* BhC = BBASE(t); \
    const char* AhN = ABASE((t) + 1); const char* BhN = BBASE((t) + 1); \
    /* q0 */ LGKM0(); RD_Ax(An, AhC, 1); if (G1) STG_B((t) + 1, 1); \
    SETP1(); MMQ(Ac, Bc, 0, 0); SETP0(); BAR(); \
    /* q1 */ LGKM0(); RD_Bx(Bn, BhC, 1); \
    SETP1(); MMQ(An, Bc, 1, 0); SETP0(); BAR(); \
    /* q2 */ LGKM0(); if (G2) STG_A((t) + 2, 0); \
    SETP1(); MMQ(An, Bn, 1, 1); SETP0(); \
    if (G2) { VMCNT(2); } else { VMCNT(0); } BAR(); \
    /* q3 */ if (G1) { RD_Ax(An, AhN, 0); RD_Bx(Bc, BhN, 0); } \
    if (G2) { STG_A((t) + 2, 1); STG_B((t) + 2, 0); } \
    SETP1(); MMQ(Ac, Bn, 0, 1); SETP0(); BAR(); }

__global__ __launch_bounds__(512, 2) void gemm_kernel(const __bf16* __restrict__ A,
                                                      const __bf16* __restrict__ B,
                                                      __bf16* __restrict__ Y, long r0) {
  __shared__ __align__(16) __bf16 As[2 * 2 * 8192];   // [buf][half][128][64] swizzled
  __shared__ __align__(16) __bf16 Bs[2 * 2 * 8192];

  const int tid  = threadIdx.x;
  const int lane = tid & 63;
  const int wid  = tid >> 6;        // 0..7
  const int wr   = wid >> 2;        // 0..1  (M half)
  const int wc   = wid & 3;         // 0..3  (N quarter)

  // bijective XCD-aware swizzle (m204)
  const int nwg = gridDim.x;
  const int q8 = nwg >> 3, r8 = nwg & 7;
  const int xcd = blockIdx.x & 7, rest = blockIdx.x >> 3;
  const int wgid = (xcd < r8 ? xcd * (q8 + 1) : r8 * (q8 + 1) + (xcd - r8) * q8) + rest;
  const long m0 = (long)(wgid >> 4) * 256;   // chunk-local row tile
  const long n0 = (long)(wgid & 15) * 256;

  // staging: linear dest (row=tid/8, slot=tid&7); inverse-swizzled global source:
  // source col slot = (tid&7) ^ ((tid>>3)&7). (+64-row half: row mod 8 unchanged.)
  const int scol = (((tid & 7) ^ ((tid >> 3) & 7)) << 4);
  const char* Ag = (const char*)(A + (r0 + m0) * KDIM) + (long)(tid >> 3) * 2048 + scol;
  const char* Bg = (const char*)(B + n0 * KDIM) + (long)(tid >> 3) * 2048 + scol;
  char* Al = (char*)As + tid * 16;
  char* Bl = (char*)Bs + tid * 16;

  // fragment read addressing: byte = row*128 + (slot<<4), slot ^= (row&7) = (fr&7)
  const int fr  = lane & 15;
  const int sw  = (fr & 7) << 4;
  const int cb0 = (((lane >> 4) << 4)) ^ sw;
  const int cb1 = (64 | ((lane >> 4) << 4)) ^ sw;
  const int brow0 = (wc & 1) << 6;

  f32x4 acc[8][4];
  const f32x4 z = {0.f, 0.f, 0.f, 0.f};
#pragma unroll
  for (int i = 0; i < 8; ++i)
#pragma unroll
    for (int j = 0; j < 4; ++j) acc[i][j] = z;

  bf16x8 A0[4][2], A1[4][2], B0[2][2], B1[2][2];

  // ---- prologue: buf0 full + A(1) + B(1,h0) = 14 loads; wait the 8 oldest.
  STG_A(0, 0); STG_A(0, 1); STG_B(0, 0); STG_B(0, 1);
  STG_A(1, 0); STG_A(1, 1); STG_B(1, 0);
  VMCNT(6);
  BAR();
  RD_Ax(A0, ABASE(0), 0); RD_Bx(B0, BBASE(0), 0);   // q0(0) pre-reads

#pragma unroll 1
  for (int tt = 0; tt < 7; ++tt) {
    const int t = tt * 2;
    TILE(t,     A0, A1, B0, B1, true, true);
    TILE(t + 1, A1, A0, B0, B1, true, true);
  }
  TILE(14, A0, A1, B0, B1, true,  false);
  TILE(15, A1, A0, B0, B1, false, false);

  // ---- epilogue: C/D layout col=lane&15, row=(lane>>4)*4+reg
  const long mrow = m0 + wr * 128 + ((lane >> 4) << 2);
  const long ncol = n0 + wc * 64 + fr;
  __bf16* Yp = Y + mrow * NCOLS + ncol;
#pragma unroll
  for (int c = 0; c < 2; ++c)
#pragma unroll
    for (int mi = 0; mi < 4; ++mi)
#pragma unroll
      for (int nj = 0; nj < 4; ++nj)
#pragma unroll
        for (int r = 0; r < 4; ++r)
          Yp[(long)(c * 64 + mi * 16 + r) * NCOLS + nj * 16] = (__bf16)acc[c * 4 + mi][nj][r];
}

// ---------------- pass 2: row LN + gates + cell LN + output ----------------
__global__ __launch_bounds__(256) void pass2_kernel(const __bf16* __restrict__ Yw,
                                                    const float* __restrict__ bi,
                                                    const float* __restrict__ g_i2h,
                                                    const float* __restrict__ g_cell,
                                                    const float* __restrict__ b_cell,
                                                    float* __restrict__ out, long r0) {
  __shared__ float p0[4096];
  __shared__ float red[8];
  const int tid  = threadIdx.x;
  const long row = r0 + blockIdx.x;           // global row (t*64 + b)
  const bf16x8* yv = (const bf16x8*)(Yw + (long)blockIdx.x * NCOLS);

  // phase 1: p = y + bi (fp32), stash in LDS, accumulate stats over 4096
  float s = 0.f, ss = 0.f;
#pragma unroll
  for (int it = 0; it < 2; ++it) {
    const int ch = tid + it * 256;            // 8-elem chunk id, 0..511
    const bf16x8 v = yv[ch];
    const float4 b0 = ((const float4*)bi)[ch * 2];
    const float4 b1 = ((const float4*)bi)[ch * 2 + 1];
    float p[8];
    p[0] = (float)v[0] + b0.x;  p[1] = (float)v[1] + b0.y;
    p[2] = (float)v[2] + b0.z;  p[3] = (float)v[3] + b0.w;
    p[4] = (float)v[4] + b1.x;  p[5] = (float)v[5] + b1.y;
    p[6] = (float)v[6] + b1.z;  p[7] = (float)v[7] + b1.w;
#pragma unroll
    for (int u = 0; u < 8; ++u) {
      p0[ch * 8 + u] = p[u];
      s += p[u];
      ss += p[u] * p[u];
    }
  }
  block_reduce2(s, ss, red, tid);             // also fences p0 writes
  const float mu  = s * (1.f / 4096.f);
  const float var = (ss - 4096.f * mu * mu) * (1.f / 4095.f);   // ddof=1
  const float rs  = rsqrtf(var + 1e-6f);

  // phase 2: gates + cell accumulation (j = tid + u*256)
  float cc[4], oo[4];
  float s2 = 0.f, ss2 = 0.f;
#pragma unroll
  for (int u = 0; u < 4; ++u) {
    const int j = tid + u * 256;
    const float pf = g_i2h[1024 + j] * ((p0[1024 + j] - mu) * rs) + g_Cvec[1024 + j];
    const float po = g_i2h[2048 + j] * ((p0[2048 + j] - mu) * rs) + g_Cvec[2048 + j];
    const float pg = g_i2h[3072 + j] * ((p0[3072 + j] - mu) * rs) + g_Cvec[3072 + j];
    const float f  = 1.f / (1.f + __expf(-pf));
    oo[u] = 1.f / (1.f + __expf(-po));
    const float e2 = __expf(2.f * pg);
    const float gt = (e2 - 1.f) / (e2 + 1.f);   // tanh
    cc[u] = (1.f - f) * gt;                     // c0 = 0
    s2 += cc[u]; ss2 += cc[u] * cc[u];
  }
  block_reduce2(s2, ss2, red, tid);
  const float mu2  = s2 * (1.f / 1024.f);
  const float var2 = (ss2 - 1024.f * mu2 * mu2) * (1.f / 1023.f);  // ddof=1
  const float rs2  = rsqrtf(var2 + 1e-6f);

  const long obase = row * 1024;
#pragma unroll
  for (int u = 0; u < 4; ++u) {
    const int j = tid + u * 256;
    const float cn = g_cell[j] * ((cc[u] - mu2) * rs2) + b_cell[j];
    const float e2 = __expf(2.f * cn);
    const float th = (e2 - 1.f) / (e2 + 1.f);
    const float h  = oo[u] * th;
    out[obase + j] = h;
    if (row >= MROWS - 64)                       // t == T-1
      out[MROWS * 1024 + ((row - (MROWS - 64)) << 10) + j] = h;
  }
}

extern "C" void kernel_launch(void* const* d_in, const int* in_sizes, int n_in,
                              void* d_out, int out_size, void* d_ws, size_t ws_size,
                              hipStream_t stream) {
  (void)in_sizes; (void)n_in; (void)out_size;
  const float* x      = (const float*)d_in[0];
  const float* Wi     = (const float*)d_in[1];
  const float* bi     = (const float*)d_in[2];
  // d_in[3] = Wh : unused (h0 == 0)
  const float* bh     = (const float*)d_in[4];
  const float* g_i2h  = (const float*)d_in[5];
  const float* b_i2h  = (const float*)d_in[6];
  const float* g_h2h  = (const float*)d_in[7];
  const float* b_h2h  = (const float*)d_in[8];
  const float* g_cell = (const float*)d_in[9];
  const float* b_cell = (const float*)d_in[10];
  float* out = (float*)d_out;

  // All scratch in d_ws (ws >= 256MB evidence: R1-R3 held full 256MB Y there):
  //   [0, 64MB)     xb : x as bf16
  //   [64MB, 72MB)  wb : Wi as bf16
  //   [72MB, ...)   y  : Y chunk (<= 64MB)
  __bf16* xb = (__bf16*)d_ws;
  __bf16* wb = (__bf16*)((char*)d_ws + 67108864);
  __bf16* y  = (__bf16*)((char*)d_ws + 75497472);

  cast_kernel<<<2048, 256, 0, stream>>>((const float4*)x, (bf16x4*)xb, 33554432 / 4);
  cast_kernel<<<1024, 256, 0, stream>>>((const float4*)Wi, (bf16x4*)wb, 4194304 / 4);
  prep_kernel<<<1, 256, 0, stream>>>(bh, b_i2h, g_h2h, b_h2h);

  // chunk over M: cap at 8192 rows (Y chunk = 64 MB) so pass2 re-reads Y from
  // L2/L3 instead of HBM; also bounded by remaining workspace.
  long avail = (long)ws_size - 75497472L;
  long max_rows = (avail / (NCOLS * 2)) & ~255L;
  if (max_rows > 8192) max_rows = 8192;
  if (max_rows < 256)  max_rows = 256;   // assume ws >= ~74 MB
  for (long rbase = 0; rbase < MROWS; rbase += max_rows) {
    const long rows = (MROWS - rbase < max_rows) ? (MROWS - rbase) : max_rows;
    gemm_kernel<<<dim3((rows / 256) * 16), 512, 0, stream>>>(xb, wb, y, rbase);
    pass2_kernel<<<dim3(rows), 256, 0, stream>>>(y, bi, g_i2h, g_cell, b_cell, out, rbase);
  }
}